// Round 4
// baseline (298.402 us; speedup 1.0000x reference)
//
#include <hip/hip_runtime.h>
#include <math.h>

#define GAS __attribute__((address_space(1)))
#define LAS __attribute__((address_space(3)))

typedef __attribute__((ext_vector_type(4))) float f32x4;
typedef __attribute__((ext_vector_type(8))) short bf16x8;
typedef __attribute__((ext_vector_type(4))) short bf16x4;

#define MFMA(a,b,c)   __builtin_amdgcn_mfma_f32_16x16x32_bf16((a),(b),(c),0,0,0)
#define MFMA16(a,b,c) __builtin_amdgcn_mfma_f32_16x16x16bf16_1k((a),(b),(c),0,0,0)

#if __has_builtin(__builtin_amdgcn_exp2f)
#define EXP2(x) __builtin_amdgcn_exp2f(x)
#else
#define EXP2(x) exp2f(x)
#endif

__device__ __forceinline__ void gl_lds16(const void* g, void* l) {
    __builtin_amdgcn_global_load_lds((const GAS unsigned*)g, (LAS unsigned*)l, 16, 0, 0);
}

__device__ __forceinline__ short f2bf(float f) {
    union { float f; unsigned u; } v; v.f = f;
    unsigned r = (v.u + 0x7fff + ((v.u >> 16) & 1)) >> 16;   // RNE
    return (short)r;
}

__device__ __forceinline__ void castN(const float* __restrict__ s, short* __restrict__ d,
                                      int n4, int gid, int gsz) {
    for (int i = gid; i < n4; i += gsz) {
        float4 v = ((const float4*)s)[i];
        short4 o = make_short4(f2bf(v.x), f2bf(v.y), f2bf(v.z), f2bf(v.w));
        ((short4*)d)[i] = o;
    }
}

__global__ __launch_bounds__(256)
void cast_all(const float* __restrict__ x,  const float* __restrict__ wq,
              const float* __restrict__ wk, const float* __restrict__ wv,
              const float* __restrict__ wo,
              short* __restrict__ xb, short* __restrict__ wqkv, short* __restrict__ wob) {
    int gid = blockIdx.x*256 + threadIdx.x;
    int gsz = gridDim.x*256;
    castN(x,  xb,               (4096*2048)/4, gid, gsz);
    castN(wq, wqkv,             (2048*2048)/4, gid, gsz);
    castN(wk, wqkv + 2048*2048, (512*2048)/4,  gid, gsz);
    castN(wv, wqkv + 2560*2048, (512*2048)/4,  gid, gsz);
    castN(wo, wob,              (2048*2048)/4, gid, gsz);
}

// 128x256-tile bf16 MFMA GEMM, half-phase software pipeline (see round-3 notes):
// C(M,N) = A(M,K) @ Bw(N,K)^T.  512 thr = 8 waves (2M x 4N), per-wave 64x64.
// 4 LDS slots (96 KiB), stage-ahead = 3 halves, 1 barrier + counted vmcnt per half.
// XCD-aware bijective block swizzle (nwg % 8 == 0 for both dispatches).
// MODE 0: fp32 row-major to Cf (Wo path).
// MODE 1: fused QKV epilogue: RoPE via shfl_xor(1) + bf16 stores; Q pre-scaled by
//         0.125*log2e; V stored TRANSPOSED (B,8,64d,1024t).
template<int MODE>
__global__ __launch_bounds__(512, 2)
void gemm_mfma(const short* __restrict__ A, const short* __restrict__ Bw,
               int M, int N, int K, float* __restrict__ Cf,
               short* __restrict__ qo, short* __restrict__ ko, short* __restrict__ vo,
               const float* __restrict__ cosb, const float* __restrict__ sinb)
{
    __shared__ short smem[49152];   // 96 KiB: A 4x[128][32] @0, B 4x[256][32] @16384

    const int tid  = threadIdx.x;
    const int lane = tid & 63, wvi = tid >> 6;
    const int l15  = lane & 15, quad = lane >> 4;
    const int wm   = wvi >> 2,  wn   = wvi & 3;

    // XCD-aware bijective swizzle (grid.x*grid.y % 8 == 0 for all our launches)
    const int nwg = gridDim.x * gridDim.y;
    int f = blockIdx.y * gridDim.x + blockIdx.x;
    f = (f & 7) * (nwg >> 3) + (f >> 3);
    const int m0 = (f / gridDim.x) * 128, n0 = (f % gridDim.x) * 256;

    // staging lanes: row = base + (lane>>2), 16B chunk = (lane&3) ^ ((lane>>3)&3)
    const int srow   = lane >> 2;
    const int schunk = ((lane & 3) ^ ((lane >> 3) & 3)) << 3;
    const short* gA = A  + (size_t)(m0 + wvi*16 + srow)*K + schunk;
    const short* gB = Bw + (size_t)(n0 + wvi*32 + srow)*K + schunk;  // +16*K for upper 16 rows

    // fragment-read offsets (swizzled), in shorts
    const int swz     = (quad ^ ((l15 >> 1) & 3)) << 3;
    const int ardbase = (wm*64 + l15)*32 + swz;            // + mi*512 + slot*4096
    const int brdbase = 16384 + (wn*64 + l15)*32 + swz;    // + nj*512 + slot*8192

    f32x4 acc[4][4] = {};
    bf16x8 a0[4], b0[4], a1[4], b1[4];

#define SBAR  __builtin_amdgcn_s_barrier()
#define PRIO1 __builtin_amdgcn_s_setprio(1)
#define PRIO0 __builtin_amdgcn_s_setprio(0)
#define VMW(n) asm volatile("s_waitcnt vmcnt(" #n ")" ::: "memory")

#define STG(h) do { const int _s = (h)&3; const int _k = (h)<<5;                  \
    gl_lds16(gA + _k,            &smem[_s*4096 + wvi*512]);                        \
    gl_lds16(gB + _k,            &smem[16384 + _s*8192 + wvi*1024]);               \
    gl_lds16(gB + (size_t)16*K + _k, &smem[16384 + _s*8192 + wvi*1024 + 512]);     \
} while(0)

#define RD(av, bv, h) do { const int _s = (h)&3;                                   \
    _Pragma("unroll") for (int _i = 0; _i < 4; _i++)                               \
        av[_i] = *(const bf16x8*)&smem[_s*4096 + ardbase + _i*512];                \
    _Pragma("unroll") for (int _j = 0; _j < 4; _j++)                               \
        bv[_j] = *(const bf16x8*)&smem[_s*8192 + brdbase + _j*512];                \
} while(0)

#define MM(av, bv) do {                                                            \
    _Pragma("unroll") for (int _i = 0; _i < 4; _i++)                               \
    _Pragma("unroll") for (int _j = 0; _j < 4; _j++)                               \
        acc[_i][_j] = MFMA(av[_i], bv[_j], acc[_i][_j]);                           \
} while(0)

    const int H = K >> 5;            // 64 halves (K=2048), even
    // prologue: stage halves 0,1,2; retire half 0; pre-read half-0 fragments
    STG(0); STG(1); STG(2);
    VMW(6); SBAR;
    RD(a0, b0, 0);

    for (int h = 0; h < H; h += 2) {
        // ---- half h (fragments in a0/b0) ----
        if (h < H-2) { VMW(3); } else { VMW(0); }   // retire half h+1's loads
        SBAR;
        if (h+1 < H) RD(a1, b1, h+1);
        PRIO1; MM(a0, b0); PRIO0;
        if (h+3 < H) STG(h+3);
        // ---- half h+1 (fragments in a1/b1) ----
        if (h+1 < H-2) { VMW(3); } else { VMW(0); } // retire half h+2's loads
        SBAR;
        if (h+2 < H) RD(a0, b0, h+2);
        PRIO1; MM(a1, b1); PRIO0;
        if (h+4 < H) STG(h+4);
    }
#undef STG
#undef RD
#undef MM
#undef VMW

    if (MODE == 0) {
        #pragma unroll
        for (int i = 0; i < 4; i++)
            #pragma unroll
            for (int j = 0; j < 4; j++) {
                int n  = n0 + wn*64 + j*16 + l15;
                int mb = m0 + wm*64 + i*16 + quad*4;
                #pragma unroll
                for (int r = 0; r < 4; r++)
                    Cf[(size_t)(mb + r)*N + n] = acc[i][j][r];
            }
    } else {
        #pragma unroll
        for (int i = 0; i < 4; i++)
            #pragma unroll
            for (int j = 0; j < 4; j++) {
                int n  = n0 + wn*64 + j*16 + l15;   // 16-range never crosses a 64-boundary
                int mb = m0 + wm*64 + i*16 + quad*4;
                if (n >= 2560) {                     // V: transposed store, 4 consecutive t
                    int bq = mb >> 10, t0 = mb & 1023;
                    int hv = (n - 2560) >> 6, d = (n - 2560) & 63;
                    short4 s4 = make_short4(f2bf(acc[i][j][0]), f2bf(acc[i][j][1]),
                                            f2bf(acc[i][j][2]), f2bf(acc[i][j][3]));
                    *(short4*)&vo[(((size_t)(bq*8 + hv)*64 + d) << 10) + t0] = s4;
                } else {
                    #pragma unroll
                    for (int r = 0; r < 4; r++) {
                        int m = mb + r;
                        int b = m >> 10, t = m & 1023;
                        float val = acc[i][j][r];
                        float part = __shfl_xor(val, 1);
                        int d2 = (n & 63) >> 1;
                        float c = cosb[t*32 + d2], s = sinb[t*32 + d2];
                        val = (n & 1) ? (part*s + val*c) : (val*c - part*s);
                        if (n < 2048) {
                            val *= 0.18033688f;      // 64^-0.5 * log2(e)
                            qo[(((size_t)(b*32 + (n>>6))*1024 + t) << 6) + (n & 63)] = f2bf(val);
                        } else {
                            ko[(((size_t)(b*8 + ((n-2048)>>6))*1024 + t) << 6) + ((n-2048) & 63)] = f2bf(val);
                        }
                    }
                }
            }
    }
}

// GQA-fused MFMA flash attention. Block = (b, kvh, qt) = 1024 thr = 16 waves =
// 4 q-heads x 4 row-groups; K/V staged ONCE per block (4-head reuse), both
// double-buffered in LDS -> ONE barrier per 64-key chunk. Transposed-S:
// S^T = K Q^T (C-layout col=q=l15, row=key=quad*4+r) is already the 16x16x16
// B-operand layout, so P feeds O^T = V^T P^T fully in-register (no Ps buffer).
// Staging: waves 0-7 V (b128 global->reg->LDS stride 72, conflict-free),
// waves 8-15 K (1 global_load_lds dwordx4 each, m97 layout). Q from global once.
// Shift-free exp2 softmax (Q pre-scaled); mask peeled to diagonal chunk.
// launch_bounds(1024, 4): 4 waves/EU = 1 block/CU -> 128 VGPR/wave cap.
// (Previous (1024, 8) forced a 64-VGPR cap -> inner-loop scratch spills.)
__global__ __launch_bounds__(1024, 4)
void attn_mfma(const short* __restrict__ q_ws, const short* __restrict__ k_ws,
               const short* __restrict__ vt_ws, short* __restrict__ o_ws)
{
    __shared__ short Ks[2][4096];     // [kc2][64k][32d]
    __shared__ short Vs[2][4608];     // [64d][64key] stride 72

    const int tid = threadIdx.x, lane = tid & 63, wv = tid >> 6;
    const int qt = 15 - blockIdx.x;              // big tiles dispatch first
    const int kvh = blockIdx.y, b = blockIdx.z;
    const int hq = wv & 3, rgrp = wv >> 2;
    const int head = kvh*4 + hq;
    const size_t qbase  = ((size_t)(b*32 + head)) << 16;
    const size_t kvbase = ((size_t)(b*8  + kvh )) << 16;
    const short* kt = k_ws  + kvbase;
    const short* vt = vt_ws + kvbase;
    const int l15 = lane & 15, quad = lane >> 4;

    // staging roles
    const bool vstager = (tid < 512);
    const int vrow = tid >> 3, vcol = (tid & 7)*8;           // tid<512: V row d, key chunk
    const int g = tid & 511;                                  // tid>=512: K linear slot
    const int kc = g >> 8, kr = (g >> 2) & 63, dq = (g & 3)*8;

    // chunk 0
    if (vstager) {
        bf16x8 v0 = *(const bf16x8*)(vt + (size_t)vrow*1024 + vcol);
        *(bf16x8*)&Vs[0][vrow*72 + vcol] = v0;
    } else {
        gl_lds16(kt + (size_t)kr*64 + kc*32 + dq, &Ks[0][(wv - 8)*512]);
    }

    // Q B-fragments direct from global (once)
    const short* qp = q_ws + qbase + (size_t)(qt*64 + rgrp*16 + l15)*64 + quad*8;
    bf16x8 aq0 = *(const bf16x8*)qp;
    bf16x8 aq1 = *(const bf16x8*)(qp + 32);

    f32x4 o_acc[4] = {};                          // O^T: row d=quad*4+r (+16dt), col q=l15
    float lsum = 0.f;
    const int qrel = rgrp*16 + l15;

    for (int c = 0; c <= qt; c++) {
        const int cb = c & 1, nb = cb ^ 1;
        __syncthreads();                          // K[c]/V[c] visible; prev reads done
        bf16x8 vreg;
        const bool pre = (c < qt);
        if (pre) {                                // prefetch chunk c+1
            if (vstager)
                vreg = *(const bf16x8*)(vt + (size_t)vrow*1024 + (c+1)*64 + vcol);
            else
                gl_lds16(kt + (size_t)((c+1)*64 + kr)*64 + kc*32 + dq,
                         &Ks[nb][(wv - 8)*512]);
        }

        // S^T = K Q^T  (log2 domain, Q pre-scaled)
        f32x4 s_acc[4];
        #pragma unroll
        for (int nt = 0; nt < 4; nt++) {
            bf16x8 kf0 = *(const bf16x8*)&Ks[cb][(nt*16 + l15)*32 + quad*8];
            bf16x8 kf1 = *(const bf16x8*)&Ks[cb][2048 + (nt*16 + l15)*32 + quad*8];
            f32x4 z = {};
            z = MFMA(kf0, aq0, z);
            s_acc[nt] = MFMA(kf1, aq1, z);
        }

        // shift-free softmax numerators; in-register C->B transform
        bf16x4 pb[4];
        if (c == qt) {                            // diagonal chunk only: causal mask
            #pragma unroll
            for (int nt = 0; nt < 4; nt++)
                #pragma unroll
                for (int r = 0; r < 4; r++) {
                    float p = (nt*16 + quad*4 + r > qrel) ? 0.f : EXP2(s_acc[nt][r]);
                    lsum += p;
                    pb[nt][r] = f2bf(p);
                }
        } else {
            #pragma unroll
            for (int nt = 0; nt < 4; nt++)
                #pragma unroll
                for (int r = 0; r < 4; r++) {
                    float p = EXP2(s_acc[nt][r]);
                    lsum += p;
                    pb[nt][r] = f2bf(p);
                }
        }

        if (pre && vstager)                       // V regs -> LDS (latency now hidden)
            *(bf16x8*)&Vs[nb][vrow*72 + vcol] = vreg;

        // O^T += V^T P^T
        #pragma unroll
        for (int dt = 0; dt < 4; dt++)
            #pragma unroll
            for (int nt = 0; nt < 4; nt++) {
                bf16x4 vf = *(const bf16x4*)&Vs[cb][(dt*16 + l15)*72 + nt*16 + quad*4];
                o_acc[dt] = MFMA16(vf, pb[nt], o_acc[dt]);
            }
    }

    lsum += __shfl_xor(lsum, 16);                 // combine the 4 quads of this q
    lsum += __shfl_xor(lsum, 32);
    float inv = 1.f / lsum;
    short* orow = o_ws + ((size_t)(b*1024 + qt*64 + qrel))*2048 + head*64;
    #pragma unroll
    for (int dt = 0; dt < 4; dt++) {
        short4 s4 = make_short4(f2bf(o_acc[dt][0]*inv), f2bf(o_acc[dt][1]*inv),
                                f2bf(o_acc[dt][2]*inv), f2bf(o_acc[dt][3]*inv));
        *(short4*)&orow[dt*16 + quad*4] = s4;
    }
}

extern "C" void kernel_launch(void* const* d_in, const int* in_sizes, int n_in,
                              void* d_out, int out_size, void* d_ws, size_t ws_size,
                              hipStream_t stream) {
    const float* x    = (const float*)d_in[0];
    const float* cosb = (const float*)d_in[1];
    const float* sinb = (const float*)d_in[2];
    const float* Wq   = (const float*)d_in[3];
    const float* Wk   = (const float*)d_in[4];
    const float* Wv   = (const float*)d_in[5];
    const float* Wo   = (const float*)d_in[6];
    float* out = (float*)d_out;

    short* xb   = (short*)d_ws;          // 8,388,608
    short* wqkv = xb   + 8388608;        // 6,291,456  [Wq;Wk;Wv] (3072,2048)
    short* wob  = wqkv + 6291456;        // 4,194,304
    short* q_ws = wob  + 4194304;        // 8,388,608  (B,32,T,64)  pre-scaled
    short* k_ws = q_ws + 8388608;        // 2,097,152  (B,8,T,64)
    short* v_ws = k_ws + 2097152;        // 2,097,152  (B,8,64,T)  TRANSPOSED
    short* o_ws = v_ws + 2097152;        // 8,388,608  (B,T,2048)

    cast_all<<<2048, 256, 0, stream>>>(x, Wq, Wk, Wv, Wo, xb, wqkv, wob);
    gemm_mfma<1><<<dim3(12, 32), 512, 0, stream>>>(xb, wqkv, 4096, 3072, 2048,
                                                   nullptr, q_ws, k_ws, v_ws, cosb, sinb);
    attn_mfma<<<dim3(16, 8, 4), 1024, 0, stream>>>(q_ws, k_ws, v_ws, o_ws);
    gemm_mfma<0><<<dim3(8, 32), 512, 0, stream>>>(o_ws, wob, 4096, 2048, 2048,
                                                  out, nullptr, nullptr, nullptr, nullptr, nullptr);
}

// Round 5
// 279.067 us; speedup vs baseline: 1.0693x; 1.0693x over previous
//
#include <hip/hip_runtime.h>
#include <math.h>

#define GAS __attribute__((address_space(1)))
#define LAS __attribute__((address_space(3)))

typedef __attribute__((ext_vector_type(4))) float f32x4;
typedef __attribute__((ext_vector_type(8))) short bf16x8;
typedef __attribute__((ext_vector_type(4))) short bf16x4;

#define MFMA(a,b,c)   __builtin_amdgcn_mfma_f32_16x16x32_bf16((a),(b),(c),0,0,0)
#define MFMA16(a,b,c) __builtin_amdgcn_mfma_f32_16x16x16bf16_1k((a),(b),(c),0,0,0)

#if __has_builtin(__builtin_amdgcn_exp2f)
#define EXP2(x) __builtin_amdgcn_exp2f(x)
#else
#define EXP2(x) exp2f(x)
#endif

__device__ __forceinline__ void gl_lds16(const void* g, void* l) {
    __builtin_amdgcn_global_load_lds((const GAS unsigned*)g, (LAS unsigned*)l, 16, 0, 0);
}

__device__ __forceinline__ short f2bf(float f) {
    union { float f; unsigned u; } v; v.f = f;
    unsigned r = (v.u + 0x7fff + ((v.u >> 16) & 1)) >> 16;   // RNE
    return (short)r;
}

__device__ __forceinline__ void castN(const float* __restrict__ s, short* __restrict__ d,
                                      int n4, int gid, int gsz) {
    for (int i = gid; i < n4; i += gsz) {
        float4 v = ((const float4*)s)[i];
        short4 o = make_short4(f2bf(v.x), f2bf(v.y), f2bf(v.z), f2bf(v.w));
        ((short4*)d)[i] = o;
    }
}

__global__ __launch_bounds__(256)
void cast_all(const float* __restrict__ x,  const float* __restrict__ wq,
              const float* __restrict__ wk, const float* __restrict__ wv,
              const float* __restrict__ wo,
              short* __restrict__ xb, short* __restrict__ wqkv, short* __restrict__ wob) {
    int gid = blockIdx.x*256 + threadIdx.x;
    int gsz = gridDim.x*256;
    castN(x,  xb,               (4096*2048)/4, gid, gsz);
    castN(wq, wqkv,             (2048*2048)/4, gid, gsz);
    castN(wk, wqkv + 2048*2048, (512*2048)/4,  gid, gsz);
    castN(wv, wqkv + 2560*2048, (512*2048)/4,  gid, gsz);
    castN(wo, wob,              (2048*2048)/4, gid, gsz);
}

// 128x128-tile bf16 MFMA GEMM: C(M,N) = A(M,K) @ Bw(N,K)^T.
// 256 thr = 4 waves (2M x 2N), per-wave 64x64 output (acc 4x4), BK=32 phases.
// 3-slot LDS ring (48 KiB -> 3 blocks/CU = 12 waves/CU: keeps the m114
// cross-block MFMA/stage overlap that the 1-block/CU configs lost), stage-ahead
// 2, counted vmcnt(4) in the main loop (never a vmcnt(0) drain until tail).
// Conflict-free LDS: 16B-chunk XOR swizzle applied on the pre-swizzled GLOBAL
// source (linear global_load_lds dest) and on the ds_read address (measured 0
// conflicts, rounds 2-4).
// MODE 0: fp32 row-major to Cf (Wo path).
// MODE 1: fused QKV epilogue: RoPE via shfl_xor(1) + bf16 stores; Q pre-scaled by
//         0.125*log2e; V stored TRANSPOSED (B,8,64d,1024t).
template<int MODE>
__global__ __launch_bounds__(256, 3)
void gemm_mfma(const short* __restrict__ A, const short* __restrict__ Bw,
               int M, int N, int K, float* __restrict__ Cf,
               short* __restrict__ qo, short* __restrict__ ko, short* __restrict__ vo,
               const float* __restrict__ cosb, const float* __restrict__ sinb)
{
    __shared__ short smem[24576];   // 48 KiB: 3 slots x (A[128][32] | B[128][32])

    const int tid  = threadIdx.x;
    const int lane = tid & 63, wvi = tid >> 6;
    const int l15  = lane & 15, quad = lane >> 4;
    const int wm   = wvi >> 1,  wn   = wvi & 1;
    const int m0   = blockIdx.y * 128, n0 = blockIdx.x * 128;

    // staging: per wave 2 gl_lds16 for A (16 rows each) + 2 for B.
    // row = base + (lane>>2); fetched 16B chunk pre-swizzled: (lane&3)^((lane>>3)&3)
    const int srow   = lane >> 2;
    const int schunk = ((lane & 3) ^ ((lane >> 3) & 3)) << 3;
    const short* gA = A  + (size_t)(m0 + wvi*32 + srow)*K + schunk;
    const short* gB = Bw + (size_t)(n0 + wvi*32 + srow)*K + schunk;

    // fragment-read offsets (swizzled), in shorts.  slot base = s*8192.
    const int swz     = (quad ^ ((l15 >> 1) & 3)) << 3;
    const int ardbase = (wm*64 + l15)*32 + swz;            // + mi*512
    const int brdbase = 4096 + (wn*64 + l15)*32 + swz;     // + nj*512

    f32x4 acc[4][4] = {};

#define SBAR  __builtin_amdgcn_s_barrier()
#define PRIO1 __builtin_amdgcn_s_setprio(1)
#define PRIO0 __builtin_amdgcn_s_setprio(0)
#define VMW(n) asm volatile("s_waitcnt vmcnt(" #n ")" ::: "memory")

#define STG(h, s) do { const int _k = (h)<<5;                                      \
    gl_lds16(gA + _k,                 &smem[(s)*8192 + wvi*1024]);                 \
    gl_lds16(gA + (size_t)16*K + _k,  &smem[(s)*8192 + wvi*1024 + 512]);           \
    gl_lds16(gB + _k,                 &smem[(s)*8192 + 4096 + wvi*1024]);          \
    gl_lds16(gB + (size_t)16*K + _k,  &smem[(s)*8192 + 4096 + wvi*1024 + 512]);    \
} while(0)

    const int H = K >> 5;            // 64 phases (K=2048)

    // prologue: stage slots for h=0,1 (A0,A0',B0,B0',A1,A1',B1,B1');
    // VMW(4) retires slot-0's four loads.
    STG(0, 0); STG(1, 1);
    VMW(4); SBAR;

    int sc = 0;                       // slot of phase h
    for (int h = 0; h < H; ++h) {
        bf16x8 a[4], b[4];
        const int sb = sc*8192;
        #pragma unroll
        for (int i = 0; i < 4; i++) a[i] = *(const bf16x8*)&smem[sb + ardbase + i*512];
        #pragma unroll
        for (int j = 0; j < 4; j++) b[j] = *(const bf16x8*)&smem[sb + brdbase + j*512];

        if (h + 2 < H) {              // stage phase h+2 into the slot being retired
            int s2 = sc + 2; if (s2 >= 3) s2 -= 3;
            STG(h + 2, s2);
        }

        PRIO1;
        #pragma unroll
        for (int i = 0; i < 4; i++)
            #pragma unroll
            for (int j = 0; j < 4; j++) acc[i][j] = MFMA(a[i], b[j], acc[i][j]);
        PRIO0;

        // retire slot h+1 before next phase reads it:
        //   h <= H-3: outstanding = {h+1, h+2} = 8  -> VMW(4)
        //   h == H-2: outstanding = {h+1}      = 4  -> VMW(0)
        //   h == H-1: nothing outstanding           -> skip
        if (h + 2 < H)      { VMW(4); }
        else if (h + 1 < H) { VMW(0); }
        SBAR;
        sc = (sc == 2) ? 0 : sc + 1;
    }
#undef STG
#undef VMW

    if (MODE == 0) {
        #pragma unroll
        for (int i = 0; i < 4; i++)
            #pragma unroll
            for (int j = 0; j < 4; j++) {
                int n  = n0 + wn*64 + j*16 + l15;
                int mb = m0 + wm*64 + i*16 + quad*4;
                #pragma unroll
                for (int r = 0; r < 4; r++)
                    Cf[(size_t)(mb + r)*N + n] = acc[i][j][r];
            }
    } else {
        #pragma unroll
        for (int i = 0; i < 4; i++)
            #pragma unroll
            for (int j = 0; j < 4; j++) {
                int n  = n0 + wn*64 + j*16 + l15;   // 16-range never crosses a 64-boundary
                int mb = m0 + wm*64 + i*16 + quad*4;
                if (n >= 2560) {                     // V: transposed store, 4 consecutive t
                    int bq = mb >> 10, t0 = mb & 1023;
                    int hv = (n - 2560) >> 6, d = (n - 2560) & 63;
                    short4 s4 = make_short4(f2bf(acc[i][j][0]), f2bf(acc[i][j][1]),
                                            f2bf(acc[i][j][2]), f2bf(acc[i][j][3]));
                    *(short4*)&vo[(((size_t)(bq*8 + hv)*64 + d) << 10) + t0] = s4;
                } else {
                    #pragma unroll
                    for (int r = 0; r < 4; r++) {
                        int m = mb + r;
                        int b = m >> 10, t = m & 1023;
                        float val = acc[i][j][r];
                        float part = __shfl_xor(val, 1);
                        int d2 = (n & 63) >> 1;
                        float c = cosb[t*32 + d2], s = sinb[t*32 + d2];
                        val = (n & 1) ? (part*s + val*c) : (val*c - part*s);
                        if (n < 2048) {
                            val *= 0.18033688f;      // 64^-0.5 * log2(e)
                            qo[(((size_t)(b*32 + (n>>6))*1024 + t) << 6) + (n & 63)] = f2bf(val);
                        } else {
                            ko[(((size_t)(b*8 + ((n-2048)>>6))*1024 + t) << 6) + ((n-2048) & 63)] = f2bf(val);
                        }
                    }
                }
            }
    }
}

// GQA-fused MFMA flash attention. Block = (b, kvh, qt) = 1024 thr = 16 waves =
// 4 q-heads x 4 row-groups; K/V staged ONCE per block (4-head reuse), both
// double-buffered in LDS -> ONE barrier per 64-key chunk. Transposed-S:
// S^T = K Q^T (C-layout col=q=l15, row=key=quad*4+r) is already the 16x16x16
// B-operand layout, so P feeds O^T = V^T P^T fully in-register (no Ps buffer).
// Staging: waves 0-7 V (b128 global->reg->LDS stride 72, conflict-free),
// waves 8-15 K (1 global_load_lds dwordx4 each, m97 layout). Q from global once.
// Shift-free exp2 softmax (Q pre-scaled); mask peeled to diagonal chunk.
// launch_bounds(1024, 8): 64-VGPR waves -> 2 blocks/CU, all 512 blocks resident
// (measured round 3/4: this beats the 128-VGPR 1-block/CU variant).
__global__ __launch_bounds__(1024, 8)
void attn_mfma(const short* __restrict__ q_ws, const short* __restrict__ k_ws,
               const short* __restrict__ vt_ws, short* __restrict__ o_ws)
{
    __shared__ short Ks[2][4096];     // [kc2][64k][32d]
    __shared__ short Vs[2][4608];     // [64d][64key] stride 72

    const int tid = threadIdx.x, lane = tid & 63, wv = tid >> 6;
    const int qt = 15 - blockIdx.x;              // big tiles dispatch first
    const int kvh = blockIdx.y, b = blockIdx.z;
    const int hq = wv & 3, rgrp = wv >> 2;
    const int head = kvh*4 + hq;
    const size_t qbase  = ((size_t)(b*32 + head)) << 16;
    const size_t kvbase = ((size_t)(b*8  + kvh )) << 16;
    const short* kt = k_ws  + kvbase;
    const short* vt = vt_ws + kvbase;
    const int l15 = lane & 15, quad = lane >> 4;

    // staging roles
    const bool vstager = (tid < 512);
    const int vrow = tid >> 3, vcol = (tid & 7)*8;           // tid<512: V row d, key chunk
    const int g = tid & 511;                                  // tid>=512: K linear slot
    const int kc = g >> 8, kr = (g >> 2) & 63, dq = (g & 3)*8;

    // chunk 0
    if (vstager) {
        bf16x8 v0 = *(const bf16x8*)(vt + (size_t)vrow*1024 + vcol);
        *(bf16x8*)&Vs[0][vrow*72 + vcol] = v0;
    } else {
        gl_lds16(kt + (size_t)kr*64 + kc*32 + dq, &Ks[0][(wv - 8)*512]);
    }

    // Q B-fragments direct from global (once)
    const short* qp = q_ws + qbase + (size_t)(qt*64 + rgrp*16 + l15)*64 + quad*8;
    bf16x8 aq0 = *(const bf16x8*)qp;
    bf16x8 aq1 = *(const bf16x8*)(qp + 32);

    f32x4 o_acc[4] = {};                          // O^T: row d=quad*4+r (+16dt), col q=l15
    float lsum = 0.f;
    const int qrel = rgrp*16 + l15;

    for (int c = 0; c <= qt; c++) {
        const int cb = c & 1, nb = cb ^ 1;
        __syncthreads();                          // K[c]/V[c] visible; prev reads done
        bf16x8 vreg;
        const bool pre = (c < qt);
        if (pre) {                                // prefetch chunk c+1
            if (vstager)
                vreg = *(const bf16x8*)(vt + (size_t)vrow*1024 + (c+1)*64 + vcol);
            else
                gl_lds16(kt + (size_t)((c+1)*64 + kr)*64 + kc*32 + dq,
                         &Ks[nb][(wv - 8)*512]);
        }

        // S^T = K Q^T  (log2 domain, Q pre-scaled)
        f32x4 s_acc[4];
        #pragma unroll
        for (int nt = 0; nt < 4; nt++) {
            bf16x8 kf0 = *(const bf16x8*)&Ks[cb][(nt*16 + l15)*32 + quad*8];
            bf16x8 kf1 = *(const bf16x8*)&Ks[cb][2048 + (nt*16 + l15)*32 + quad*8];
            f32x4 z = {};
            z = MFMA(kf0, aq0, z);
            s_acc[nt] = MFMA(kf1, aq1, z);
        }

        // shift-free softmax numerators; in-register C->B transform
        bf16x4 pb[4];
        if (c == qt) {                            // diagonal chunk only: causal mask
            #pragma unroll
            for (int nt = 0; nt < 4; nt++)
                #pragma unroll
                for (int r = 0; r < 4; r++) {
                    float p = (nt*16 + quad*4 + r > qrel) ? 0.f : EXP2(s_acc[nt][r]);
                    lsum += p;
                    pb[nt][r] = f2bf(p);
                }
        } else {
            #pragma unroll
            for (int nt = 0; nt < 4; nt++)
                #pragma unroll
                for (int r = 0; r < 4; r++) {
                    float p = EXP2(s_acc[nt][r]);
                    lsum += p;
                    pb[nt][r] = f2bf(p);
                }
        }

        if (pre && vstager)                       // V regs -> LDS (latency now hidden)
            *(bf16x8*)&Vs[nb][vrow*72 + vcol] = vreg;

        // O^T += V^T P^T
        #pragma unroll
        for (int dt = 0; dt < 4; dt++)
            #pragma unroll
            for (int nt = 0; nt < 4; nt++) {
                bf16x4 vf = *(const bf16x4*)&Vs[cb][(dt*16 + l15)*72 + nt*16 + quad*4];
                o_acc[dt] = MFMA16(vf, pb[nt], o_acc[dt]);
            }
    }

    lsum += __shfl_xor(lsum, 16);                 // combine the 4 quads of this q
    lsum += __shfl_xor(lsum, 32);
    float inv = 1.f / lsum;
    short* orow = o_ws + ((size_t)(b*1024 + qt*64 + qrel))*2048 + head*64;
    #pragma unroll
    for (int dt = 0; dt < 4; dt++) {
        short4 s4 = make_short4(f2bf(o_acc[dt][0]*inv), f2bf(o_acc[dt][1]*inv),
                                f2bf(o_acc[dt][2]*inv), f2bf(o_acc[dt][3]*inv));
        *(short4*)&orow[dt*16 + quad*4] = s4;
    }
}

extern "C" void kernel_launch(void* const* d_in, const int* in_sizes, int n_in,
                              void* d_out, int out_size, void* d_ws, size_t ws_size,
                              hipStream_t stream) {
    const float* x    = (const float*)d_in[0];
    const float* cosb = (const float*)d_in[1];
    const float* sinb = (const float*)d_in[2];
    const float* Wq   = (const float*)d_in[3];
    const float* Wk   = (const float*)d_in[4];
    const float* Wv   = (const float*)d_in[5];
    const float* Wo   = (const float*)d_in[6];
    float* out = (float*)d_out;

    short* xb   = (short*)d_ws;          // 8,388,608
    short* wqkv = xb   + 8388608;        // 6,291,456  [Wq;Wk;Wv] (3072,2048)
    short* wob  = wqkv + 6291456;        // 4,194,304
    short* q_ws = wob  + 4194304;        // 8,388,608  (B,32,T,64)  pre-scaled
    short* k_ws = q_ws + 8388608;        // 2,097,152  (B,8,T,64)
    short* v_ws = k_ws + 2097152;        // 2,097,152  (B,8,64,T)  TRANSPOSED
    short* o_ws = v_ws + 2097152;        // 8,388,608  (B,T,2048)

    cast_all<<<2048, 256, 0, stream>>>(x, Wq, Wk, Wv, Wo, xb, wqkv, wob);
    gemm_mfma<1><<<dim3(24, 32), 256, 0, stream>>>(xb, wqkv, 4096, 3072, 2048,
                                                   nullptr, q_ws, k_ws, v_ws, cosb, sinb);
    attn_mfma<<<dim3(16, 8, 4), 1024, 0, stream>>>(q_ws, k_ws, v_ws, o_ws);
    gemm_mfma<0><<<dim3(16, 32), 256, 0, stream>>>(o_ws, wob, 4096, 2048, 2048,
                                                   out, nullptr, nullptr, nullptr, nullptr, nullptr);
}

// Round 6
// 264.384 us; speedup vs baseline: 1.1287x; 1.0555x over previous
//
#include <hip/hip_runtime.h>
#include <math.h>

#define GAS __attribute__((address_space(1)))
#define LAS __attribute__((address_space(3)))

typedef __attribute__((ext_vector_type(4))) float f32x4;
typedef __attribute__((ext_vector_type(8))) short bf16x8;
typedef __attribute__((ext_vector_type(4))) short bf16x4;

#define MFMA(a,b,c)   __builtin_amdgcn_mfma_f32_16x16x32_bf16((a),(b),(c),0,0,0)
#define MFMA16(a,b,c) __builtin_amdgcn_mfma_f32_16x16x16bf16_1k((a),(b),(c),0,0,0)

#if __has_builtin(__builtin_amdgcn_exp2f)
#define EXP2(x) __builtin_amdgcn_exp2f(x)
#else
#define EXP2(x) exp2f(x)
#endif

__device__ __forceinline__ void gl_lds16(const void* g, void* l) {
    __builtin_amdgcn_global_load_lds((const GAS unsigned*)g, (LAS unsigned*)l, 16, 0, 0);
}

__device__ __forceinline__ short f2bf(float f) {
    union { float f; unsigned u; } v; v.f = f;
    unsigned r = (v.u + 0x7fff + ((v.u >> 16) & 1)) >> 16;   // RNE
    return (short)r;
}

__device__ __forceinline__ void castN(const float* __restrict__ s, short* __restrict__ d,
                                      int n4, int gid, int gsz) {
    for (int i = gid; i < n4; i += gsz) {
        float4 v = ((const float4*)s)[i];
        short4 o = make_short4(f2bf(v.x), f2bf(v.y), f2bf(v.z), f2bf(v.w));
        ((short4*)d)[i] = o;
    }
}

__global__ __launch_bounds__(256)
void cast_all(const float* __restrict__ x,  const float* __restrict__ wq,
              const float* __restrict__ wk, const float* __restrict__ wv,
              const float* __restrict__ wo,
              short* __restrict__ xb, short* __restrict__ wqkv, short* __restrict__ wob) {
    int gid = blockIdx.x*256 + threadIdx.x;
    int gsz = gridDim.x*256;
    castN(x,  xb,               (4096*2048)/4, gid, gsz);
    castN(wq, wqkv,             (2048*2048)/4, gid, gsz);
    castN(wk, wqkv + 2048*2048, (512*2048)/4,  gid, gsz);
    castN(wv, wqkv + 2560*2048, (512*2048)/4,  gid, gsz);
    castN(wo, wob,              (2048*2048)/4, gid, gsz);
}

// 128x128-tile bf16 MFMA GEMM: C(M,N) = A(M,K) @ Bw(N,K)^T.
// 256 thr = 4 waves (2M x 2N), per-wave 64x64 output (acc 4x4), BK=32 phases.
// 3-slot LDS ring (48 KiB -> 3 blocks/CU = 12 waves/CU: keeps the m114
// cross-block MFMA/stage overlap), stage-ahead 2, counted vmcnt(4) in the main
// loop (never a vmcnt(0) drain until tail).  Conflict-free LDS: 16B-chunk XOR
// swizzle on pre-swizzled GLOBAL source + ds_read addr (measured 0 conflicts).
// Measured r5: 78.5 us QKV, MfmaUtil 27.5 -- best of 6 structural variants.
// MODE 0: fp32 row-major to Cf (Wo path).
// MODE 1: fused QKV epilogue: RoPE via shfl_xor(1) + bf16 stores; Q pre-scaled by
//         0.125*log2e; V stored TRANSPOSED (B,8,64d,1024t).
template<int MODE>
__global__ __launch_bounds__(256, 3)
void gemm_mfma(const short* __restrict__ A, const short* __restrict__ Bw,
               int M, int N, int K, float* __restrict__ Cf,
               short* __restrict__ qo, short* __restrict__ ko, short* __restrict__ vo,
               const float* __restrict__ cosb, const float* __restrict__ sinb)
{
    __shared__ short smem[24576];   // 48 KiB: 3 slots x (A[128][32] | B[128][32])

    const int tid  = threadIdx.x;
    const int lane = tid & 63, wvi = tid >> 6;
    const int l15  = lane & 15, quad = lane >> 4;
    const int wm   = wvi >> 1,  wn   = wvi & 1;
    const int m0   = blockIdx.y * 128, n0 = blockIdx.x * 128;

    // staging: per wave 2 gl_lds16 for A (16 rows each) + 2 for B.
    // row = base + (lane>>2); fetched 16B chunk pre-swizzled: (lane&3)^((lane>>3)&3)
    const int srow   = lane >> 2;
    const int schunk = ((lane & 3) ^ ((lane >> 3) & 3)) << 3;
    const short* gA = A  + (size_t)(m0 + wvi*32 + srow)*K + schunk;
    const short* gB = Bw + (size_t)(n0 + wvi*32 + srow)*K + schunk;

    // fragment-read offsets (swizzled), in shorts.  slot base = s*8192.
    const int swz     = (quad ^ ((l15 >> 1) & 3)) << 3;
    const int ardbase = (wm*64 + l15)*32 + swz;            // + mi*512
    const int brdbase = 4096 + (wn*64 + l15)*32 + swz;     // + nj*512

    f32x4 acc[4][4] = {};

#define SBAR  __builtin_amdgcn_s_barrier()
#define PRIO1 __builtin_amdgcn_s_setprio(1)
#define PRIO0 __builtin_amdgcn_s_setprio(0)
#define VMW(n) asm volatile("s_waitcnt vmcnt(" #n ")" ::: "memory")

#define STG(h, s) do { const int _k = (h)<<5;                                      \
    gl_lds16(gA + _k,                 &smem[(s)*8192 + wvi*1024]);                 \
    gl_lds16(gA + (size_t)16*K + _k,  &smem[(s)*8192 + wvi*1024 + 512]);           \
    gl_lds16(gB + _k,                 &smem[(s)*8192 + 4096 + wvi*1024]);          \
    gl_lds16(gB + (size_t)16*K + _k,  &smem[(s)*8192 + 4096 + wvi*1024 + 512]);    \
} while(0)

    const int H = K >> 5;            // 64 phases (K=2048)

    // prologue: stage slots for h=0,1; VMW(4) retires slot-0's four loads.
    STG(0, 0); STG(1, 1);
    VMW(4); SBAR;

    int sc = 0;                       // slot of phase h
    for (int h = 0; h < H; ++h) {
        bf16x8 a[4], b[4];
        const int sb = sc*8192;
        #pragma unroll
        for (int i = 0; i < 4; i++) a[i] = *(const bf16x8*)&smem[sb + ardbase + i*512];
        #pragma unroll
        for (int j = 0; j < 4; j++) b[j] = *(const bf16x8*)&smem[sb + brdbase + j*512];

        if (h + 2 < H) {              // stage phase h+2 into the slot being retired
            int s2 = sc + 2; if (s2 >= 3) s2 -= 3;
            STG(h + 2, s2);
        }

        PRIO1;
        #pragma unroll
        for (int i = 0; i < 4; i++)
            #pragma unroll
            for (int j = 0; j < 4; j++) acc[i][j] = MFMA(a[i], b[j], acc[i][j]);
        PRIO0;

        // retire slot h+1 before next phase reads it:
        //   h <= H-3: outstanding = {h+1, h+2} = 8  -> VMW(4)
        //   h == H-2: outstanding = {h+1}      = 4  -> VMW(0)
        //   h == H-1: nothing outstanding           -> skip
        if (h + 2 < H)      { VMW(4); }
        else if (h + 1 < H) { VMW(0); }
        SBAR;
        sc = (sc == 2) ? 0 : sc + 1;
    }
#undef STG
#undef VMW

    if (MODE == 0) {
        #pragma unroll
        for (int i = 0; i < 4; i++)
            #pragma unroll
            for (int j = 0; j < 4; j++) {
                int n  = n0 + wn*64 + j*16 + l15;
                int mb = m0 + wm*64 + i*16 + quad*4;
                #pragma unroll
                for (int r = 0; r < 4; r++)
                    Cf[(size_t)(mb + r)*N + n] = acc[i][j][r];
            }
    } else {
        #pragma unroll
        for (int i = 0; i < 4; i++)
            #pragma unroll
            for (int j = 0; j < 4; j++) {
                int n  = n0 + wn*64 + j*16 + l15;   // 16-range never crosses a 64-boundary
                int mb = m0 + wm*64 + i*16 + quad*4;
                if (n >= 2560) {                     // V: transposed store, 4 consecutive t
                    int bq = mb >> 10, t0 = mb & 1023;
                    int hv = (n - 2560) >> 6, d = (n - 2560) & 63;
                    short4 s4 = make_short4(f2bf(acc[i][j][0]), f2bf(acc[i][j][1]),
                                            f2bf(acc[i][j][2]), f2bf(acc[i][j][3]));
                    *(short4*)&vo[(((size_t)(bq*8 + hv)*64 + d) << 10) + t0] = s4;
                } else {
                    #pragma unroll
                    for (int r = 0; r < 4; r++) {
                        int m = mb + r;
                        int b = m >> 10, t = m & 1023;
                        float val = acc[i][j][r];
                        float part = __shfl_xor(val, 1);
                        int d2 = (n & 63) >> 1;
                        float c = cosb[t*32 + d2], s = sinb[t*32 + d2];
                        val = (n & 1) ? (part*s + val*c) : (val*c - part*s);
                        if (n < 2048) {
                            val *= 0.18033688f;      // 64^-0.5 * log2(e)
                            qo[(((size_t)(b*32 + (n>>6))*1024 + t) << 6) + (n & 63)] = f2bf(val);
                        } else {
                            ko[(((size_t)(b*8 + ((n-2048)>>6))*1024 + t) << 6) + ((n-2048) & 63)] = f2bf(val);
                        }
                    }
                }
            }
    }
}

// GQA-fused MFMA flash attention. Block = (b, kvh, qtile) = 1024 thr = 16 waves =
// 4 q-heads x 4 row-groups; K/V staged ONCE per block (4-head reuse), both
// double-buffered in LDS -> ONE barrier per 64-key chunk. Transposed-S:
// S^T = K Q^T (C-layout col=q=l15, row=key=quad*4+r) is already the 16x16x16
// B-operand layout, so P feeds O^T = V^T P^T fully in-register (no Ps buffer).
// Staging: waves 0-7 V (b128 global->reg->LDS stride 72, conflict-free),
// waves 8-15 K (1 global_load_lds dwordx4 each, m97 layout). Q from global once.
// Shift-free exp2 softmax (Q pre-scaled); mask peeled to diagonal chunk.
// launch_bounds(1024, 8): 64-VGPR waves -> 2 blocks/CU, all 512 blocks resident.
// LOAD BALANCE: work per block is proportional to qt+1 (causal). Co-resident
// blocks are linear ids i and i+256 = same (bx,y), z+2 under round-robin (both
// flat-%256 and XCD-interleaved models). qt = (z&2) ? bx : 15-bx makes each
// co-resident pair sum to 17 chunk-iters (uniform makespan; was same-qt pairs
// -> straggler CUs carried 32 while mean was 17).
__global__ __launch_bounds__(1024, 8)
void attn_mfma(const short* __restrict__ q_ws, const short* __restrict__ k_ws,
               const short* __restrict__ vt_ws, short* __restrict__ o_ws)
{
    __shared__ short Ks[2][4096];     // [kc2][64k][32d]
    __shared__ short Vs[2][4608];     // [64d][64key] stride 72

    const int tid = threadIdx.x, lane = tid & 63, wv = tid >> 6;
    const int qt = (blockIdx.z & 2) ? blockIdx.x : (15 - blockIdx.x);
    const int kvh = blockIdx.y, b = blockIdx.z;
    const int hq = wv & 3, rgrp = wv >> 2;
    const int head = kvh*4 + hq;
    const size_t qbase  = ((size_t)(b*32 + head)) << 16;
    const size_t kvbase = ((size_t)(b*8  + kvh )) << 16;
    const short* kt = k_ws  + kvbase;
    const short* vt = vt_ws + kvbase;
    const int l15 = lane & 15, quad = lane >> 4;

    // staging roles
    const bool vstager = (tid < 512);
    const int vrow = tid >> 3, vcol = (tid & 7)*8;           // tid<512: V row d, key chunk
    const int g = tid & 511;                                  // tid>=512: K linear slot
    const int kc = g >> 8, kr = (g >> 2) & 63, dq = (g & 3)*8;

    // chunk 0
    if (vstager) {
        bf16x8 v0 = *(const bf16x8*)(vt + (size_t)vrow*1024 + vcol);
        *(bf16x8*)&Vs[0][vrow*72 + vcol] = v0;
    } else {
        gl_lds16(kt + (size_t)kr*64 + kc*32 + dq, &Ks[0][(wv - 8)*512]);
    }

    // Q B-fragments direct from global (once)
    const short* qp = q_ws + qbase + (size_t)(qt*64 + rgrp*16 + l15)*64 + quad*8;
    bf16x8 aq0 = *(const bf16x8*)qp;
    bf16x8 aq1 = *(const bf16x8*)(qp + 32);

    f32x4 o_acc[4] = {};                          // O^T: row d=quad*4+r (+16dt), col q=l15
    float lsum = 0.f;
    const int qrel = rgrp*16 + l15;

    for (int c = 0; c <= qt; c++) {
        const int cb = c & 1, nb = cb ^ 1;
        __syncthreads();                          // K[c]/V[c] visible; prev reads done
        bf16x8 vreg;
        const bool pre = (c < qt);
        if (pre) {                                // prefetch chunk c+1
            if (vstager)
                vreg = *(const bf16x8*)(vt + (size_t)vrow*1024 + (c+1)*64 + vcol);
            else
                gl_lds16(kt + (size_t)((c+1)*64 + kr)*64 + kc*32 + dq,
                         &Ks[nb][(wv - 8)*512]);
        }

        // S^T = K Q^T  (log2 domain, Q pre-scaled)
        f32x4 s_acc[4];
        #pragma unroll
        for (int nt = 0; nt < 4; nt++) {
            bf16x8 kf0 = *(const bf16x8*)&Ks[cb][(nt*16 + l15)*32 + quad*8];
            bf16x8 kf1 = *(const bf16x8*)&Ks[cb][2048 + (nt*16 + l15)*32 + quad*8];
            f32x4 z = {};
            z = MFMA(kf0, aq0, z);
            s_acc[nt] = MFMA(kf1, aq1, z);
        }

        // shift-free softmax numerators; in-register C->B transform
        bf16x4 pb[4];
        if (c == qt) {                            // diagonal chunk only: causal mask
            #pragma unroll
            for (int nt = 0; nt < 4; nt++)
                #pragma unroll
                for (int r = 0; r < 4; r++) {
                    float p = (nt*16 + quad*4 + r > qrel) ? 0.f : EXP2(s_acc[nt][r]);
                    lsum += p;
                    pb[nt][r] = f2bf(p);
                }
        } else {
            #pragma unroll
            for (int nt = 0; nt < 4; nt++)
                #pragma unroll
                for (int r = 0; r < 4; r++) {
                    float p = EXP2(s_acc[nt][r]);
                    lsum += p;
                    pb[nt][r] = f2bf(p);
                }
        }

        if (pre && vstager)                       // V regs -> LDS (latency now hidden)
            *(bf16x8*)&Vs[nb][vrow*72 + vcol] = vreg;

        // O^T += V^T P^T
        #pragma unroll
        for (int dt = 0; dt < 4; dt++)
            #pragma unroll
            for (int nt = 0; nt < 4; nt++) {
                bf16x4 vf = *(const bf16x4*)&Vs[cb][(dt*16 + l15)*72 + nt*16 + quad*4];
                o_acc[dt] = MFMA16(vf, pb[nt], o_acc[dt]);
            }
    }

    lsum += __shfl_xor(lsum, 16);                 // combine the 4 quads of this q
    lsum += __shfl_xor(lsum, 32);
    float inv = 1.f / lsum;
    short* orow = o_ws + ((size_t)(b*1024 + qt*64 + qrel))*2048 + head*64;
    #pragma unroll
    for (int dt = 0; dt < 4; dt++) {
        short4 s4 = make_short4(f2bf(o_acc[dt][0]*inv), f2bf(o_acc[dt][1]*inv),
                                f2bf(o_acc[dt][2]*inv), f2bf(o_acc[dt][3]*inv));
        *(short4*)&orow[dt*16 + quad*4] = s4;
    }
}

extern "C" void kernel_launch(void* const* d_in, const int* in_sizes, int n_in,
                              void* d_out, int out_size, void* d_ws, size_t ws_size,
                              hipStream_t stream) {
    const float* x    = (const float*)d_in[0];
    const float* cosb = (const float*)d_in[1];
    const float* sinb = (const float*)d_in[2];
    const float* Wq   = (const float*)d_in[3];
    const float* Wk   = (const float*)d_in[4];
    const float* Wv   = (const float*)d_in[5];
    const float* Wo   = (const float*)d_in[6];
    float* out = (float*)d_out;

    short* xb   = (short*)d_ws;          // 8,388,608
    short* wqkv = xb   + 8388608;        // 6,291,456  [Wq;Wk;Wv] (3072,2048)
    short* wob  = wqkv + 6291456;        // 4,194,304
    short* q_ws = wob  + 4194304;        // 8,388,608  (B,32,T,64)  pre-scaled
    short* k_ws = q_ws + 8388608;        // 2,097,152  (B,8,T,64)
    short* v_ws = k_ws + 2097152;        // 2,097,152  (B,8,64,T)  TRANSPOSED
    short* o_ws = v_ws + 2097152;        // 8,388,608  (B,T,2048)

    cast_all<<<2048, 256, 0, stream>>>(x, Wq, Wk, Wv, Wo, xb, wqkv, wob);
    gemm_mfma<1><<<dim3(24, 32), 256, 0, stream>>>(xb, wqkv, 4096, 3072, 2048,
                                                   nullptr, q_ws, k_ws, v_ws, cosb, sinb);
    attn_mfma<<<dim3(16, 8, 4), 1024, 0, stream>>>(q_ws, k_ws, v_ws, o_ws);
    gemm_mfma<0><<<dim3(16, 32), 256, 0, stream>>>(o_ws, wob, 4096, 2048, 2048,
                                                   out, nullptr, nullptr, nullptr, nullptr, nullptr);
}

// Round 7
// 262.714 us; speedup vs baseline: 1.1358x; 1.0064x over previous
//
#include <hip/hip_runtime.h>
#include <math.h>

#define GAS __attribute__((address_space(1)))
#define LAS __attribute__((address_space(3)))

typedef __attribute__((ext_vector_type(4))) float f32x4;
typedef __attribute__((ext_vector_type(8))) short bf16x8;
typedef __attribute__((ext_vector_type(4))) short bf16x4;

#define MFMA(a,b,c)   __builtin_amdgcn_mfma_f32_16x16x32_bf16((a),(b),(c),0,0,0)
#define MFMA16(a,b,c) __builtin_amdgcn_mfma_f32_16x16x16bf16_1k((a),(b),(c),0,0,0)

#if __has_builtin(__builtin_amdgcn_exp2f)
#define EXP2(x) __builtin_amdgcn_exp2f(x)
#else
#define EXP2(x) exp2f(x)
#endif

__device__ __forceinline__ void gl_lds16(const void* g, void* l) {
    __builtin_amdgcn_global_load_lds((const GAS unsigned*)g, (LAS unsigned*)l, 16, 0, 0);
}

__device__ __forceinline__ short f2bf(float f) {
    union { float f; unsigned u; } v; v.f = f;
    unsigned r = (v.u + 0x7fff + ((v.u >> 16) & 1)) >> 16;   // RNE
    return (short)r;
}

__device__ __forceinline__ void castN(const float* __restrict__ s, short* __restrict__ d,
                                      int n4, int gid, int gsz) {
    for (int i = gid; i < n4; i += gsz) {
        float4 v = ((const float4*)s)[i];
        short4 o = make_short4(f2bf(v.x), f2bf(v.y), f2bf(v.z), f2bf(v.w));
        ((short4*)d)[i] = o;
    }
}

__global__ __launch_bounds__(256)
void cast_all(const float* __restrict__ x,  const float* __restrict__ wq,
              const float* __restrict__ wk, const float* __restrict__ wv,
              const float* __restrict__ wo,
              short* __restrict__ xb, short* __restrict__ wqkv, short* __restrict__ wob) {
    int gid = blockIdx.x*256 + threadIdx.x;
    int gsz = gridDim.x*256;
    castN(x,  xb,               (4096*2048)/4, gid, gsz);
    castN(wq, wqkv,             (2048*2048)/4, gid, gsz);
    castN(wk, wqkv + 2048*2048, (512*2048)/4,  gid, gsz);
    castN(wv, wqkv + 2560*2048, (512*2048)/4,  gid, gsz);
    castN(wo, wob,              (2048*2048)/4, gid, gsz);
}

// 128x128-tile bf16 MFMA GEMM, 8-WAVE blocks: C(M,N) = A(M,K) @ Bw(N,K)^T.
// 512 thr = 8 waves (2M x 4N), per-wave 64x32 output (acc 4x2), BK=32 phases.
// WHY 8 waves: round 2-6 showed per-CU phase time ~ serial SUM of pipe times
// (MFMA 931 + LDS 1525 + VALU 590 cyc) at 12 waves/CU (3 waves/SIMD) -- pipes
// under 55% busy but latency chains don't interleave. Same grid (768 = 3
// blocks/CU) with 8-wave blocks = 24 waves/CU (6/SIMD) to overlap the pipes.
// 3-slot LDS ring (48 KiB -> 3 blocks/CU), stage-ahead 2, counted vmcnt(2)
// (never a drain-to-0 until tail). Conflict-free LDS: 16B-chunk XOR swizzle on
// pre-swizzled GLOBAL source + ds_read addr (measured 0 conflicts, rounds 2-6).
// MODE 0: fp32 row-major to Cf (Wo path).
// MODE 1: fused QKV epilogue: RoPE via shfl_xor(1) + bf16 stores; Q pre-scaled by
//         0.125*log2e; V stored TRANSPOSED (B,8,64d,1024t).
template<int MODE>
__global__ __launch_bounds__(512, 6)
void gemm_mfma(const short* __restrict__ A, const short* __restrict__ Bw,
               int M, int N, int K, float* __restrict__ Cf,
               short* __restrict__ qo, short* __restrict__ ko, short* __restrict__ vo,
               const float* __restrict__ cosb, const float* __restrict__ sinb)
{
    __shared__ short smem[24576];   // 48 KiB: 3 slots x (A[128][32] | B[128][32])

    const int tid  = threadIdx.x;
    const int lane = tid & 63, wvi = tid >> 6;        // 8 waves
    const int l15  = lane & 15, quad = lane >> 4;
    const int wm   = wvi >> 2,  wn   = wvi & 3;       // 2M x 4N
    const int m0   = blockIdx.y * 128, n0 = blockIdx.x * 128;

    // staging: wave w stages A rows [w*16..w*16+15] (1 KiB) + B rows likewise.
    // lane l: row = w*16 + (l>>2), 16B chunk = (l&3) ^ ((l>>3)&3)  (pre-swizzled
    // source, linear LDS dest; involution verified vs read-side swz).
    const int srow   = lane >> 2;
    const int schunk = ((lane & 3) ^ ((lane >> 3) & 3)) << 3;
    const short* gA = A  + (size_t)(m0 + wvi*16 + srow)*K + schunk;
    const short* gB = Bw + (size_t)(n0 + wvi*16 + srow)*K + schunk;

    // fragment-read offsets (swizzled), in shorts.  slot base = s*8192.
    const int swz     = (quad ^ ((l15 >> 1) & 3)) << 3;
    const int ardbase = (wm*64 + l15)*32 + swz;            // + mi*512
    const int brdbase = 4096 + (wn*32 + l15)*32 + swz;     // + nj*512

    f32x4 acc[4][2] = {};

#define SBAR  __builtin_amdgcn_s_barrier()
#define PRIO1 __builtin_amdgcn_s_setprio(1)
#define PRIO0 __builtin_amdgcn_s_setprio(0)
#define VMW(n) asm volatile("s_waitcnt vmcnt(" #n ")" ::: "memory")

#define STG(h, s) do { const int _k = (h)<<5;                                      \
    gl_lds16(gA + _k,  &smem[(s)*8192 + wvi*512]);                                 \
    gl_lds16(gB + _k,  &smem[(s)*8192 + 4096 + wvi*512]);                          \
} while(0)

    const int H = K >> 5;            // 64 phases (K=2048)

    // prologue: stage slots 0,1; VMW(2) retires slot-0's two loads.
    STG(0, 0); STG(1, 1);
    VMW(2); SBAR;

    int sc = 0;                       // slot of phase h
    for (int h = 0; h < H; ++h) {
        bf16x8 a[4], b[2];
        const int sb = sc*8192;
        #pragma unroll
        for (int i = 0; i < 4; i++) a[i] = *(const bf16x8*)&smem[sb + ardbase + i*512];
        #pragma unroll
        for (int j = 0; j < 2; j++) b[j] = *(const bf16x8*)&smem[sb + brdbase + j*512];

        if (h + 2 < H) {              // stage phase h+2 into the slot being retired
            int s2 = sc + 2; if (s2 >= 3) s2 -= 3;
            STG(h + 2, s2);
        }

        PRIO1;
        #pragma unroll
        for (int i = 0; i < 4; i++)
            #pragma unroll
            for (int j = 0; j < 2; j++) acc[i][j] = MFMA(a[i], b[j], acc[i][j]);
        PRIO0;

        // retire slot h+1 before next phase reads it (2 loads/phase):
        //   h <= H-3: outstanding = {h+1, h+2} = 4  -> VMW(2)
        //   h == H-2: outstanding = {h+1}      = 2  -> VMW(0)
        //   h == H-1: nothing outstanding           -> skip
        if (h + 2 < H)      { VMW(2); }
        else if (h + 1 < H) { VMW(0); }
        SBAR;
        sc = (sc == 2) ? 0 : sc + 1;
    }
#undef STG
#undef VMW

    if (MODE == 0) {
        #pragma unroll
        for (int i = 0; i < 4; i++)
            #pragma unroll
            for (int j = 0; j < 2; j++) {
                int n  = n0 + wn*32 + j*16 + l15;
                int mb = m0 + wm*64 + i*16 + quad*4;
                #pragma unroll
                for (int r = 0; r < 4; r++)
                    Cf[(size_t)(mb + r)*N + n] = acc[i][j][r];
            }
    } else {
        #pragma unroll
        for (int i = 0; i < 4; i++)
            #pragma unroll
            for (int j = 0; j < 2; j++) {
                int n  = n0 + wn*32 + j*16 + l15;   // 16-range never crosses a 64-boundary
                int mb = m0 + wm*64 + i*16 + quad*4;
                if (n >= 2560) {                     // V: transposed store, 4 consecutive t
                    int bq = mb >> 10, t0 = mb & 1023;
                    int hv = (n - 2560) >> 6, d = (n - 2560) & 63;
                    short4 s4 = make_short4(f2bf(acc[i][j][0]), f2bf(acc[i][j][1]),
                                            f2bf(acc[i][j][2]), f2bf(acc[i][j][3]));
                    *(short4*)&vo[(((size_t)(bq*8 + hv)*64 + d) << 10) + t0] = s4;
                } else {
                    #pragma unroll
                    for (int r = 0; r < 4; r++) {
                        int m = mb + r;
                        int b = m >> 10, t = m & 1023;
                        float val = acc[i][j][r];
                        float part = __shfl_xor(val, 1);
                        int d2 = (n & 63) >> 1;
                        float c = cosb[t*32 + d2], s = sinb[t*32 + d2];
                        val = (n & 1) ? (part*s + val*c) : (val*c - part*s);
                        if (n < 2048) {
                            val *= 0.18033688f;      // 64^-0.5 * log2(e)
                            qo[(((size_t)(b*32 + (n>>6))*1024 + t) << 6) + (n & 63)] = f2bf(val);
                        } else {
                            ko[(((size_t)(b*8 + ((n-2048)>>6))*1024 + t) << 6) + ((n-2048) & 63)] = f2bf(val);
                        }
                    }
                }
            }
    }
}

// GQA-fused MFMA flash attention. Block = (b, kvh, qtile) = 1024 thr = 16 waves =
// 4 q-heads x 4 row-groups; K/V staged ONCE per block (4-head reuse), both
// double-buffered in LDS -> ONE barrier per 64-key chunk. Transposed-S:
// S^T = K Q^T (C-layout col=q=l15, row=key=quad*4+r) is already the 16x16x16
// B-operand layout, so P feeds O^T = V^T P^T fully in-register (no Ps buffer).
// Staging: waves 0-7 V (b128 global->reg->LDS stride 72, conflict-free),
// waves 8-15 K (1 global_load_lds dwordx4 each, m97 layout). Q from global once.
// Shift-free exp2 softmax (Q pre-scaled); mask peeled to diagonal chunk.
// launch_bounds(1024, 8): 64-VGPR waves -> 2 blocks/CU, all 512 blocks resident.
// LOAD BALANCE: qt = (z&2) ? bx : 15-bx -> co-resident pairs sum to 17 chunks
// (measured r6: -15 us total vs same-qt pairs).
__global__ __launch_bounds__(1024, 8)
void attn_mfma(const short* __restrict__ q_ws, const short* __restrict__ k_ws,
               const short* __restrict__ vt_ws, short* __restrict__ o_ws)
{
    __shared__ short Ks[2][4096];     // [kc2][64k][32d]
    __shared__ short Vs[2][4608];     // [64d][64key] stride 72

    const int tid = threadIdx.x, lane = tid & 63, wv = tid >> 6;
    const int qt = (blockIdx.z & 2) ? blockIdx.x : (15 - blockIdx.x);
    const int kvh = blockIdx.y, b = blockIdx.z;
    const int hq = wv & 3, rgrp = wv >> 2;
    const int head = kvh*4 + hq;
    const size_t qbase  = ((size_t)(b*32 + head)) << 16;
    const size_t kvbase = ((size_t)(b*8  + kvh )) << 16;
    const short* kt = k_ws  + kvbase;
    const short* vt = vt_ws + kvbase;
    const int l15 = lane & 15, quad = lane >> 4;

    // staging roles
    const bool vstager = (tid < 512);
    const int vrow = tid >> 3, vcol = (tid & 7)*8;           // tid<512: V row d, key chunk
    const int g = tid & 511;                                  // tid>=512: K linear slot
    const int kc = g >> 8, kr = (g >> 2) & 63, dq = (g & 3)*8;

    // chunk 0
    if (vstager) {
        bf16x8 v0 = *(const bf16x8*)(vt + (size_t)vrow*1024 + vcol);
        *(bf16x8*)&Vs[0][vrow*72 + vcol] = v0;
    } else {
        gl_lds16(kt + (size_t)kr*64 + kc*32 + dq, &Ks[0][(wv - 8)*512]);
    }

    // Q B-fragments direct from global (once)
    const short* qp = q_ws + qbase + (size_t)(qt*64 + rgrp*16 + l15)*64 + quad*8;
    bf16x8 aq0 = *(const bf16x8*)qp;
    bf16x8 aq1 = *(const bf16x8*)(qp + 32);

    f32x4 o_acc[4] = {};                          // O^T: row d=quad*4+r (+16dt), col q=l15
    float lsum = 0.f;
    const int qrel = rgrp*16 + l15;

    for (int c = 0; c <= qt; c++) {
        const int cb = c & 1, nb = cb ^ 1;
        __syncthreads();                          // K[c]/V[c] visible; prev reads done
        bf16x8 vreg;
        const bool pre = (c < qt);
        if (pre) {                                // prefetch chunk c+1
            if (vstager)
                vreg = *(const bf16x8*)(vt + (size_t)vrow*1024 + (c+1)*64 + vcol);
            else
                gl_lds16(kt + (size_t)((c+1)*64 + kr)*64 + kc*32 + dq,
                         &Ks[nb][(wv - 8)*512]);
        }

        // S^T = K Q^T  (log2 domain, Q pre-scaled)
        f32x4 s_acc[4];
        #pragma unroll
        for (int nt = 0; nt < 4; nt++) {
            bf16x8 kf0 = *(const bf16x8*)&Ks[cb][(nt*16 + l15)*32 + quad*8];
            bf16x8 kf1 = *(const bf16x8*)&Ks[cb][2048 + (nt*16 + l15)*32 + quad*8];
            f32x4 z = {};
            z = MFMA(kf0, aq0, z);
            s_acc[nt] = MFMA(kf1, aq1, z);
        }

        // shift-free softmax numerators; in-register C->B transform
        bf16x4 pb[4];
        if (c == qt) {                            // diagonal chunk only: causal mask
            #pragma unroll
            for (int nt = 0; nt < 4; nt++)
                #pragma unroll
                for (int r = 0; r < 4; r++) {
                    float p = (nt*16 + quad*4 + r > qrel) ? 0.f : EXP2(s_acc[nt][r]);
                    lsum += p;
                    pb[nt][r] = f2bf(p);
                }
        } else {
            #pragma unroll
            for (int nt = 0; nt < 4; nt++)
                #pragma unroll
                for (int r = 0; r < 4; r++) {
                    float p = EXP2(s_acc[nt][r]);
                    lsum += p;
                    pb[nt][r] = f2bf(p);
                }
        }

        if (pre && vstager)                       // V regs -> LDS (latency now hidden)
            *(bf16x8*)&Vs[nb][vrow*72 + vcol] = vreg;

        // O^T += V^T P^T
        #pragma unroll
        for (int dt = 0; dt < 4; dt++)
            #pragma unroll
            for (int nt = 0; nt < 4; nt++) {
                bf16x4 vf = *(const bf16x4*)&Vs[cb][(dt*16 + l15)*72 + nt*16 + quad*4];
                o_acc[dt] = MFMA16(vf, pb[nt], o_acc[dt]);
            }
    }

    lsum += __shfl_xor(lsum, 16);                 // combine the 4 quads of this q
    lsum += __shfl_xor(lsum, 32);
    float inv = 1.f / lsum;
    short* orow = o_ws + ((size_t)(b*1024 + qt*64 + qrel))*2048 + head*64;
    #pragma unroll
    for (int dt = 0; dt < 4; dt++) {
        short4 s4 = make_short4(f2bf(o_acc[dt][0]*inv), f2bf(o_acc[dt][1]*inv),
                                f2bf(o_acc[dt][2]*inv), f2bf(o_acc[dt][3]*inv));
        *(short4*)&orow[dt*16 + quad*4] = s4;
    }
}

extern "C" void kernel_launch(void* const* d_in, const int* in_sizes, int n_in,
                              void* d_out, int out_size, void* d_ws, size_t ws_size,
                              hipStream_t stream) {
    const float* x    = (const float*)d_in[0];
    const float* cosb = (const float*)d_in[1];
    const float* sinb = (const float*)d_in[2];
    const float* Wq   = (const float*)d_in[3];
    const float* Wk   = (const float*)d_in[4];
    const float* Wv   = (const float*)d_in[5];
    const float* Wo   = (const float*)d_in[6];
    float* out = (float*)d_out;

    short* xb   = (short*)d_ws;          // 8,388,608
    short* wqkv = xb   + 8388608;        // 6,291,456  [Wq;Wk;Wv] (3072,2048)
    short* wob  = wqkv + 6291456;        // 4,194,304
    short* q_ws = wob  + 4194304;        // 8,388,608  (B,32,T,64)  pre-scaled
    short* k_ws = q_ws + 8388608;        // 2,097,152  (B,8,T,64)
    short* v_ws = k_ws + 2097152;        // 2,097,152  (B,8,64,T)  TRANSPOSED
    short* o_ws = v_ws + 2097152;        // 8,388,608  (B,T,2048)

    cast_all<<<2048, 256, 0, stream>>>(x, Wq, Wk, Wv, Wo, xb, wqkv, wob);
    gemm_mfma<1><<<dim3(24, 32), 512, 0, stream>>>(xb, wqkv, 4096, 3072, 2048,
                                                   nullptr, q_ws, k_ws, v_ws, cosb, sinb);
    attn_mfma<<<dim3(16, 8, 4), 1024, 0, stream>>>(q_ws, k_ws, v_ws, o_ws);
    gemm_mfma<0><<<dim3(16, 32), 512, 0, stream>>>(o_ws, wob, 4096, 2048, 2048,
                                                   out, nullptr, nullptr, nullptr, nullptr, nullptr);
}